// Round 6
// baseline (150.746 us; speedup 1.0000x reference)
//
#include <hip/hip_runtime.h>
#include <stdint.h>

// B=2,H=16 -> BH=32; S=2048, D=64. chunk_size telescopes out:
// out = causal attention with phi(s)=s+0.5*s^2, s=(q*D^-0.5).k
#define SEQ  2048
#define DH   64
#define BH_N 32
#define SCALE 0.125f

typedef __attribute__((ext_vector_type(8))) short short8;   // 8 bf16
typedef __attribute__((ext_vector_type(4))) float f32x4;    // MFMA C/D

static __device__ __forceinline__ unsigned short f2bf(float f) {
  unsigned int u = __float_as_uint(f);
  u += 0x7fffu + ((u >> 16) & 1u);   // RNE
  return (unsigned short)(u >> 16);
}
// HW packed f32->bf16 (RNE), 1 instr per pair: d.lo=bf16(a), d.hi=bf16(b)
static __device__ __forceinline__ unsigned cvtpk(float a, float b) {
  unsigned r;
  asm("v_cvt_pk_bf16_f32 %0, %1, %2" : "=v"(r) : "v"(a), "v"(b));
  return r;
}

// ---------------------------------------------------------------------------
// Prep: per (bh, 64-key tile) produce 16B-unit-packed tiles (512 units/tile).
// KEY PERMUTATION: tile row position pos(k) = (k&32)|((k&4)<<2)|((k&24)>>1)|(k&3)
// (inverse: actual key at pos n*16+row = 32*(n>>1)+(row>>2)*8+(n&1)*4+(row&3)).
// With this order, the two QK sub-tile outputs nt=2a,2a+1 leave lane (quad,low)
// holding S^T for actual keys a*32+quad*8+{0..7} == a 16x16x32 B-fragment, so
// PV runs as full-K mfma_f32_16x16x32_bf16 with no operand shuffles.
//  kb2 unit u = c*64+pos (c=ks*4+quad): shorts j = K[key][ks*32+quad*8+j] (bf16)
//  vt2 unit u = a*256+ft*64+quad*16+low: shorts j = V[a*32+quad*8+j][ft*16+low]
// ---------------------------------------------------------------------------
__global__ __launch_bounds__(256) void prep_kernel(
    const float* __restrict__ kin, const float* __restrict__ vin,
    unsigned short* __restrict__ kb2, unsigned short* __restrict__ vt2)
{
  const int sb = blockIdx.x;    // 0..31 (64 keys each)
  const int bh = blockIdx.y;    // 0..31
  const int t  = threadIdx.x;   // 0..255
  __shared__ __align__(16) unsigned short lds[4096];
  const size_t base  = ((size_t)bh * SEQ + (size_t)sb * 64) * DH;
  const size_t obase = ((size_t)bh * 32 + sb) * 4096;   // shorts per tile

  // ---- K ----
  #pragma unroll
  for (int i = 0; i < 4; ++i) {
    int idx = i * 256 + t, key = idx >> 4, F = (idx & 15) * 4;
    float4 f = *reinterpret_cast<const float4*>(kin + base + key * DH + F);
    int pos = (key & 32) | ((key & 4) << 2) | ((key & 24) >> 1) | (key & 3);
    int c = (F >> 5) * 4 + ((F >> 3) & 3), jh = (F >> 2) & 1;
    uint2 pk; pk.x = cvtpk(f.x, f.y); pk.y = cvtpk(f.z, f.w);
    *reinterpret_cast<uint2*>(lds + (c * 64 + pos) * 8 + jh * 4) = pk;
  }
  __syncthreads();
  #pragma unroll
  for (int uu = 0; uu < 2; ++uu) {
    int u = uu * 256 + t;
    *reinterpret_cast<uint4*>(kb2 + obase + u * 8) =
        *reinterpret_cast<const uint4*>(lds + u * 8);
  }
  __syncthreads();
  // ---- V ----
  #pragma unroll
  for (int i = 0; i < 4; ++i) {
    int idx = i * 256 + t, key = idx >> 4, F = (idx & 15) * 4;
    float4 f = *reinterpret_cast<const float4*>(vin + base + key * DH + F);
    int a = key >> 5, qd = (key >> 3) & 3, jj = key & 7;
    int u0 = a * 256 + (F >> 4) * 64 + qd * 16 + (F & 15);
    lds[(u0 + 0) * 8 + jj] = f2bf(f.x);
    lds[(u0 + 1) * 8 + jj] = f2bf(f.y);
    lds[(u0 + 2) * 8 + jj] = f2bf(f.z);
    lds[(u0 + 3) * 8 + jj] = f2bf(f.w);
  }
  __syncthreads();
  #pragma unroll
  for (int uu = 0; uu < 2; ++uu) {
    int u = uu * 256 + t;
    *reinterpret_cast<uint4*>(vt2 + obase + u * 8) =
        *reinterpret_cast<const uint4*>(lds + u * 8);
  }
}

// ---------------------------------------------------------------------------
// attn: grid (16,32), 256 threads (4 waves). XCD-aware remap (bijective,
// 512 = 64 x 8): XCD c owns bh in {4c..4c+3}. R2/R4/R5 PMC: KV reads are
// 100% L2/L3-hit (FETCH ~= q only, 16.4 MB).
//
// Barrier-free + REGISTER DOUBLE-BUFFER SW PIPELINE. R5 was latency-bound
// (46.8us vs ~16us L2-stream floor): loads inside the branchy slot body
// couldn't be hoisted across slots by the compiler. Now PRELOAD(T) issues
// slot s+2's 16 global_load_dwordx4 into named register arrays BEFORE slot
// s's COMPUTE; one full slot of MFMA+VALU (~600+ cyc) hides the L2/L3
// latency. Two named buffer sets (kf0/vf0, kf1/vf1), loop unrolled by 2 for
// static register indexing (no scratch).
//
// Block owns q-tiles A=qa, B=31-qa. Flat slot list (33): s<nB -> (B, kv=s);
// else (A, kv=s-nB), nB=32-qa. Wave w: p=w>>1 -> slots s=p,p+2,..,<=32;
// rh=w&1 -> 32 q-rows. S^T = K.Q^T (16x16x32, key-permuted rows) -> phi in
// register -> cvt_pk to K=32 P^T B-frags -> O^T += V^T.P^T (16x16x32).
// Split-K parity merged once via 32 KB LDS at the end.
// ---------------------------------------------------------------------------
__global__ __launch_bounds__(256, 2) void attn_kernel(
    const float* __restrict__ q,
    const unsigned short* __restrict__ kb2,
    const unsigned short* __restrict__ vt2,
    float* __restrict__ out)
{
  const int lid  = blockIdx.y * 16 + blockIdx.x;   // hw dispatch order
  const int xcd  = lid & 7;
  const int jj_  = lid >> 3;                       // 0..63
  const int bh   = (xcd << 2) | (jj_ >> 4);        // 4 bh per XCD
  const int qa   = jj_ & 15;
  const int tid  = threadIdx.x;
  const int w    = tid >> 6;          // 0..3
  const int lane = tid & 63;
  const int low  = lane & 15;
  const int quad = lane >> 4;
  const int p    = w >> 1;            // slot parity
  const int rh   = w & 1;             // q-row half
  const int nB   = 32 - qa;           // number of B-steps

  __shared__ __align__(16) float mls[8192];        // 32 KB merge buffer

  const unsigned short* kb_h = kb2 + (size_t)bh * 32 * 4096;
  const unsigned short* v2_h = vt2 + (size_t)bh * 32 * 4096;

  // Q B-frags for both tiles (scaled bf16), registers for whole kernel
  short8 aqA[2][2], aqB[2][2];
  #pragma unroll
  for (int tsel = 0; tsel < 2; ++tsel) {
    const int qt = tsel ? (31 - qa) : qa;
    #pragma unroll
    for (int h = 0; h < 2; ++h) {
      const float* qp =
          q + ((size_t)bh * SEQ + qt * 64 + rh * 32 + h * 16 + low) * DH + quad * 8;
      #pragma unroll
      for (int ks = 0; ks < 2; ++ks) {
        float4 f0 = *reinterpret_cast<const float4*>(qp + ks * 32);
        float4 f1 = *reinterpret_cast<const float4*>(qp + ks * 32 + 4);
        uint4 uv;
        uv.x = cvtpk(f0.x * SCALE, f0.y * SCALE);
        uv.y = cvtpk(f0.z * SCALE, f0.w * SCALE);
        uv.z = cvtpk(f1.x * SCALE, f1.y * SCALE);
        uv.w = cvtpk(f1.z * SCALE, f1.w * SCALE);
        short8 a = __builtin_bit_cast(short8, uv);
        if (tsel) aqB[h][ks] = a; else aqA[h][ks] = a;
      }
    }
  }

  f32x4 oaccA[2][4], oaccB[2][4];
  #pragma unroll
  for (int h = 0; h < 2; ++h)
    #pragma unroll
    for (int i = 0; i < 4; ++i) {
      oaccA[h][i] = (f32x4){0.f, 0.f, 0.f, 0.f};
      oaccB[h][i] = (f32x4){0.f, 0.f, 0.f, 0.f};
    }

  // Issue the 16 dwordx4 loads for tile T into named register arrays.
  // KF[a*4+ks*2+sub] = K frag (keys (2a+sub)*16 rows, ks half of dims)
  // VF[a*4+ft]       = V frag (a group, ft feature block)
  #define PRELOAD(T, KF, VF)                                                   \
    do {                                                                       \
      const unsigned short* kTg_ = kb_h + (size_t)(T) * 4096;                  \
      const unsigned short* vTg_ = v2_h + (size_t)(T) * 4096;                  \
      _Pragma("unroll")                                                        \
      for (int a = 0; a < 2; ++a) {                                            \
        _Pragma("unroll")                                                      \
        for (int ft = 0; ft < 4; ++ft)                                         \
          VF[a * 4 + ft] = *reinterpret_cast<const short8*>(                   \
              vTg_ + ((a * 4 + ft) * 64 + lane) * 8);                          \
        _Pragma("unroll")                                                      \
        for (int ks = 0; ks < 2; ++ks) {                                       \
          KF[a * 4 + ks * 2 + 0] = *reinterpret_cast<const short8*>(           \
              kTg_ + ((ks * 4 + quad) * 64 + (a * 2 + 0) * 16 + low) * 8);     \
          KF[a * 4 + ks * 2 + 1] = *reinterpret_cast<const short8*>(           \
              kTg_ + ((ks * 4 + quad) * 64 + (a * 2 + 1) * 16 + low) * 8);     \
        }                                                                      \
      }                                                                        \
    } while (0)

  // Per 64-key group a: QK^T over two permuted 16-row sub-tiles leaves lane
  // holding S^T for actual keys a*32+quad*8+{0..7}; phi + cvt_pk builds the
  // K=32 P^T B-fragment; PV is 4 full-K MFMAs per h. Operands from registers.
  #define COMPUTE(KF, VF, AQ, OACC)                                            \
    do {                                                                       \
      _Pragma("unroll")                                                        \
      for (int a = 0; a < 2; ++a) {                                            \
        f32x4 s00 = (f32x4){0.f, 0.f, 0.f, 0.f};                               \
        f32x4 s01 = s00, s10 = s00, s11 = s00;                                 \
        _Pragma("unroll")                                                      \
        for (int ks = 0; ks < 2; ++ks) {                                       \
          s00 = __builtin_amdgcn_mfma_f32_16x16x32_bf16(                       \
              KF[a * 4 + ks * 2 + 0], AQ[0][ks], s00, 0, 0, 0);                \
          s01 = __builtin_amdgcn_mfma_f32_16x16x32_bf16(                       \
              KF[a * 4 + ks * 2 + 0], AQ[1][ks], s01, 0, 0, 0);                \
          s10 = __builtin_amdgcn_mfma_f32_16x16x32_bf16(                       \
              KF[a * 4 + ks * 2 + 1], AQ[0][ks], s10, 0, 0, 0);                \
          s11 = __builtin_amdgcn_mfma_f32_16x16x32_bf16(                       \
              KF[a * 4 + ks * 2 + 1], AQ[1][ks], s11, 0, 0, 0);                \
        }                                                                      \
        _Pragma("unroll")                                                      \
        for (int h = 0; h < 2; ++h) {                                          \
          f32x4 sA = h ? s01 : s00; /* keys a*32+quad*8+r   */                 \
          f32x4 sB = h ? s11 : s10; /* keys a*32+quad*8+4+r */                 \
          float pv[8];                                                         \
          _Pragma("unroll")                                                    \
          for (int r = 0; r < 4; ++r) {                                        \
            float x0 = sA[r], x1 = sB[r];                                      \
            pv[r]     = __builtin_fmaf(0.5f * x0, x0, x0);                     \
            pv[4 + r] = __builtin_fmaf(0.5f * x1, x1, x1);                     \
          }                                                                    \
          if (diag) {                                                          \
            const int qrow = rh * 32 + h * 16 + low;                           \
            _Pragma("unroll")                                                  \
            for (int r = 0; r < 4; ++r) {                                      \
              if ((a * 32 + quad * 8 + r) > qrow)     pv[r]     = 0.f;         \
              if ((a * 32 + quad * 8 + 4 + r) > qrow) pv[4 + r] = 0.f;         \
            }                                                                  \
          }                                                                    \
          uint4 uu;                                                            \
          uu.x = cvtpk(pv[0], pv[1]); uu.y = cvtpk(pv[2], pv[3]);              \
          uu.z = cvtpk(pv[4], pv[5]); uu.w = cvtpk(pv[6], pv[7]);              \
          short8 pf = __builtin_bit_cast(short8, uu);                          \
          _Pragma("unroll")                                                    \
          for (int ft = 0; ft < 4; ++ft)                                       \
            OACC[h][ft] = __builtin_amdgcn_mfma_f32_16x16x32_bf16(             \
                VF[a * 4 + ft], pf, OACC[h][ft], 0, 0, 0);                     \
        }                                                                      \
      }                                                                        \
    } while (0)

  // Barrier-free SW-pipelined loop: wave owns slots s = p, p+2, ..., <= 32.
  short8 kf0[8], vf0[8], kf1[8], vf1[8];
  int s = p;
  {
    const int T = (s < nB) ? s : (s - nB);
    PRELOAD(T, kf0, vf0);
  }
  for (;;) {
    int sn = s + 2;
    if (sn <= 32) {
      const int Tn = (sn < nB) ? sn : (sn - nB);
      PRELOAD(Tn, kf1, vf1);                 // in flight across compute
    }
    {
      const bool diag = (s == nB - 1) || (s == 32);
      if (s >= nB) COMPUTE(kf0, vf0, aqA, oaccA);
      else         COMPUTE(kf0, vf0, aqB, oaccB);
    }
    s = sn; if (s > 32) break;

    sn = s + 2;
    if (sn <= 32) {
      const int Tn = (sn < nB) ? sn : (sn - nB);
      PRELOAD(Tn, kf0, vf0);
    }
    {
      const bool diag = (s == nB - 1) || (s == 32);
      if (s >= nB) COMPUTE(kf1, vf1, aqA, oaccA);
      else         COMPUTE(kf1, vf1, aqB, oaccB);
    }
    s = sn; if (s > 32) break;
  }

  // ---- split-K merge via LDS (32KB) + epilogue ----
  __syncthreads();
  float* mw = mls + rh * 4096;
  if (p == 1) {
    #pragma unroll
    for (int h = 0; h < 2; ++h)
      #pragma unroll
      for (int ft = 0; ft < 4; ++ft) {
        *reinterpret_cast<f32x4*>(mw + ((0 * 8 + h * 4 + ft) * 256 + lane * 4)) =
            oaccA[h][ft];
        *reinterpret_cast<f32x4*>(mw + ((1 * 8 + h * 4 + ft) * 256 + lane * 4)) =
            oaccB[h][ft];
      }
  }
  __syncthreads();
  if (p == 0) {
    #pragma unroll
    for (int tsel = 0; tsel < 2; ++tsel) {
      const int qt = tsel ? (31 - qa) : qa;
      #pragma unroll
      for (int h = 0; h < 2; ++h)
        #pragma unroll
        for (int ft = 0; ft < 4; ++ft) {
          f32x4 o = tsel ? oaccB[h][ft] : oaccA[h][ft];
          f32x4 m = *reinterpret_cast<const f32x4*>(
              mw + ((tsel * 8 + h * 4 + ft) * 256 + lane * 4));
          o += m;
          *reinterpret_cast<f32x4*>(
              out + ((size_t)bh * SEQ + qt * 64 + rh * 32 + h * 16 + low) * DH +
              ft * 16 + quad * 4) = o;
        }
    }
  }
}

extern "C" void kernel_launch(void* const* d_in, const int* in_sizes, int n_in,
                              void* d_out, int out_size, void* d_ws, size_t ws_size,
                              hipStream_t stream)
{
  const float* q = (const float*)d_in[0];
  const float* k = (const float*)d_in[1];
  const float* v = (const float*)d_in[2];
  float* out = (float*)d_out;

  unsigned short* kb2 = (unsigned short*)d_ws;             // 8.4 MB bf16 packed
  unsigned short* vt2 = kb2 + (size_t)BH_N * SEQ * DH;     // 8.4 MB bf16 packed

  prep_kernel<<<dim3(32, BH_N), 256, 0, stream>>>(k, v, kb2, vt2);
  attn_kernel<<<dim3(16, BH_N), 256, 0, stream>>>(q, kb2, vt2, out);
}

// Round 7
// 118.923 us; speedup vs baseline: 1.2676x; 1.2676x over previous
//
#include <hip/hip_runtime.h>
#include <stdint.h>

// B=2,H=16 -> BH=32; S=2048, D=64. chunk_size telescopes out:
// out = causal attention with phi(s)=s+0.5*s^2, s=(q*D^-0.5).k
#define SEQ  2048
#define DH   64
#define BH_N 32
#define SCALE 0.125f

typedef __attribute__((ext_vector_type(8))) short short8;   // 8 bf16
typedef __attribute__((ext_vector_type(4))) float f32x4;    // MFMA C/D

static __device__ __forceinline__ unsigned short f2bf(float f) {
  unsigned int u = __float_as_uint(f);
  u += 0x7fffu + ((u >> 16) & 1u);   // RNE
  return (unsigned short)(u >> 16);
}
// HW packed f32->bf16 (RNE), 1 instr per pair: d.lo=bf16(a), d.hi=bf16(b)
static __device__ __forceinline__ unsigned cvtpk(float a, float b) {
  unsigned r;
  asm("v_cvt_pk_bf16_f32 %0, %1, %2" : "=v"(r) : "v"(a), "v"(b));
  return r;
}

// ---------------------------------------------------------------------------
// Prep: per (bh, 64-key tile) produce 16B-unit-packed tiles (512 units/tile).
// KEY PERMUTATION: tile row position pos(k) = (k&32)|((k&4)<<2)|((k&24)>>1)|(k&3)
// (inverse: actual key at pos n*16+row = 32*(n>>1)+(row>>2)*8+(n&1)*4+(row&3)).
// With this order, the two QK sub-tile outputs nt=2a,2a+1 leave lane (quad,low)
// holding S^T for actual keys a*32+quad*8+{0..7} == a 16x16x32 B-fragment, so
// PV runs as full-K mfma_f32_16x16x32_bf16 with no operand shuffles.
//  kb2 unit u = c*64+pos (c=ks*4+quad): shorts j = K[key][ks*32+quad*8+j] (bf16)
//  vt2 unit u = a*256+ft*64+quad*16+low: shorts j = V[a*32+quad*8+j][ft*16+low]
// ---------------------------------------------------------------------------
__global__ __launch_bounds__(256) void prep_kernel(
    const float* __restrict__ kin, const float* __restrict__ vin,
    unsigned short* __restrict__ kb2, unsigned short* __restrict__ vt2)
{
  const int sb = blockIdx.x;    // 0..31 (64 keys each)
  const int bh = blockIdx.y;    // 0..31
  const int t  = threadIdx.x;   // 0..255
  __shared__ __align__(16) unsigned short lds[4096];
  const size_t base  = ((size_t)bh * SEQ + (size_t)sb * 64) * DH;
  const size_t obase = ((size_t)bh * 32 + sb) * 4096;   // shorts per tile

  // ---- K ----
  #pragma unroll
  for (int i = 0; i < 4; ++i) {
    int idx = i * 256 + t, key = idx >> 4, F = (idx & 15) * 4;
    float4 f = *reinterpret_cast<const float4*>(kin + base + key * DH + F);
    int pos = (key & 32) | ((key & 4) << 2) | ((key & 24) >> 1) | (key & 3);
    int c = (F >> 5) * 4 + ((F >> 3) & 3), jh = (F >> 2) & 1;
    uint2 pk; pk.x = cvtpk(f.x, f.y); pk.y = cvtpk(f.z, f.w);
    *reinterpret_cast<uint2*>(lds + (c * 64 + pos) * 8 + jh * 4) = pk;
  }
  __syncthreads();
  #pragma unroll
  for (int uu = 0; uu < 2; ++uu) {
    int u = uu * 256 + t;
    *reinterpret_cast<uint4*>(kb2 + obase + u * 8) =
        *reinterpret_cast<const uint4*>(lds + u * 8);
  }
  __syncthreads();
  // ---- V ----
  #pragma unroll
  for (int i = 0; i < 4; ++i) {
    int idx = i * 256 + t, key = idx >> 4, F = (idx & 15) * 4;
    float4 f = *reinterpret_cast<const float4*>(vin + base + key * DH + F);
    int a = key >> 5, qd = (key >> 3) & 3, jj = key & 7;
    int u0 = a * 256 + (F >> 4) * 64 + qd * 16 + (F & 15);
    lds[(u0 + 0) * 8 + jj] = f2bf(f.x);
    lds[(u0 + 1) * 8 + jj] = f2bf(f.y);
    lds[(u0 + 2) * 8 + jj] = f2bf(f.z);
    lds[(u0 + 3) * 8 + jj] = f2bf(f.w);
  }
  __syncthreads();
  #pragma unroll
  for (int uu = 0; uu < 2; ++uu) {
    int u = uu * 256 + t;
    *reinterpret_cast<uint4*>(vt2 + obase + u * 8) =
        *reinterpret_cast<const uint4*>(lds + u * 8);
  }
}

// ---------------------------------------------------------------------------
// attn: grid (16,32), 256 threads (4 waves). XCD-aware remap (bijective,
// 512 = 64 x 8): XCD c owns bh in {4c..4c+3}. PMC (R2/R4/R5): KV reads are
// ~100% L2/L3-hit (FETCH ~= q only).
//
// Barrier-free + register double-buffer SW pipeline at 64-KEY-GROUP
// granularity. R6's full-slot double buffer (128 VGPR of buffers) blew the
// 256-reg cap and spilled (VGPR=128 + 47MB scratch writes). Group buffers
// are 8 short8 (32 VGPR) each, two of them = 64 VGPR; total demand ~200.
// Schedule per slot s: compute(s,g0) -> issue load(s+2,g0) -> compute(s,g1)
// -> issue load(s+2,g1): every load has one group-compute (16 MFMA + phi,
// ~400-600 cyc wall) of cover before use -- enough for L2/L3 service.
// Loads past s=32 clamp to T(32) (harmless).
//
// Block owns q-tiles A=qa, B=31-qa. Flat slot list (33): s<nB -> (B, kv=s);
// else (A, kv=s-nB), nB=32-qa. Wave w: p=w>>1 -> slots s=p,p+2,..,<=32;
// rh=w&1 -> 32 q-rows. S^T = K.Q^T (16x16x32, key-permuted rows) -> phi in
// register -> cvt_pk to K=32 P^T B-frags -> O^T += V^T.P^T (16x16x32).
// Split-K parity merged once via 32 KB LDS at the end.
// ---------------------------------------------------------------------------
__global__ __launch_bounds__(256, 2) void attn_kernel(
    const float* __restrict__ q,
    const unsigned short* __restrict__ kb2,
    const unsigned short* __restrict__ vt2,
    float* __restrict__ out)
{
  const int lid  = blockIdx.y * 16 + blockIdx.x;   // hw dispatch order
  const int xcd  = lid & 7;
  const int jj_  = lid >> 3;                       // 0..63
  const int bh   = (xcd << 2) | (jj_ >> 4);        // 4 bh per XCD
  const int qa   = jj_ & 15;
  const int tid  = threadIdx.x;
  const int w    = tid >> 6;          // 0..3
  const int lane = tid & 63;
  const int low  = lane & 15;
  const int quad = lane >> 4;
  const int p    = w >> 1;            // slot parity
  const int rh   = w & 1;             // q-row half
  const int nB   = 32 - qa;           // number of B-steps

  __shared__ __align__(16) float mls[8192];        // 32 KB merge buffer

  const unsigned short* kb_h = kb2 + (size_t)bh * 32 * 4096;
  const unsigned short* v2_h = vt2 + (size_t)bh * 32 * 4096;

  // Q B-frags for both tiles (scaled bf16), registers for whole kernel
  short8 aqA[2][2], aqB[2][2];
  #pragma unroll
  for (int tsel = 0; tsel < 2; ++tsel) {
    const int qt = tsel ? (31 - qa) : qa;
    #pragma unroll
    for (int h = 0; h < 2; ++h) {
      const float* qp =
          q + ((size_t)bh * SEQ + qt * 64 + rh * 32 + h * 16 + low) * DH + quad * 8;
      #pragma unroll
      for (int ks = 0; ks < 2; ++ks) {
        float4 f0 = *reinterpret_cast<const float4*>(qp + ks * 32);
        float4 f1 = *reinterpret_cast<const float4*>(qp + ks * 32 + 4);
        uint4 uv;
        uv.x = cvtpk(f0.x * SCALE, f0.y * SCALE);
        uv.y = cvtpk(f0.z * SCALE, f0.w * SCALE);
        uv.z = cvtpk(f1.x * SCALE, f1.y * SCALE);
        uv.w = cvtpk(f1.z * SCALE, f1.w * SCALE);
        short8 a = __builtin_bit_cast(short8, uv);
        if (tsel) aqB[h][ks] = a; else aqA[h][ks] = a;
      }
    }
  }

  f32x4 oaccA[2][4], oaccB[2][4];
  #pragma unroll
  for (int h = 0; h < 2; ++h)
    #pragma unroll
    for (int i = 0; i < 4; ++i) {
      oaccA[h][i] = (f32x4){0.f, 0.f, 0.f, 0.f};
      oaccB[h][i] = (f32x4){0.f, 0.f, 0.f, 0.f};
    }

  // Issue the 8 dwordx4 loads for 64-key group A of tile T.
  // KB[ks*2+sub] = K frag (keys (2A+sub)*16 rows, ks half of dims)
  // VB[ft]       = V frag (group A, ft feature block)
  #define PRELOADG(T, A, KB, VB)                                               \
    do {                                                                       \
      const unsigned short* kTg_ = kb_h + (size_t)(T) * 4096;                  \
      const unsigned short* vTg_ = v2_h + (size_t)(T) * 4096;                  \
      _Pragma("unroll")                                                        \
      for (int ft = 0; ft < 4; ++ft)                                           \
        VB[ft] = *reinterpret_cast<const short8*>(                             \
            vTg_ + (((A) * 4 + ft) * 64 + lane) * 8);                          \
      _Pragma("unroll")                                                        \
      for (int ks = 0; ks < 2; ++ks) {                                         \
        KB[ks * 2 + 0] = *reinterpret_cast<const short8*>(                     \
            kTg_ + ((ks * 4 + quad) * 64 + ((A) * 2 + 0) * 16 + low) * 8);     \
        KB[ks * 2 + 1] = *reinterpret_cast<const short8*>(                     \
            kTg_ + ((ks * 4 + quad) * 64 + ((A) * 2 + 1) * 16 + low) * 8);     \
      }                                                                        \
    } while (0)

  // Group A: QK^T over two permuted 16-row sub-tiles leaves lane holding S^T
  // for actual keys A*32+quad*8+{0..7}; phi + cvt_pk builds the K=32 P^T
  // B-fragment; PV is 4 full-K MFMAs per h. Operands from registers.
  #define COMPUTEG(KB, VB, A, AQ, OACC)                                        \
    do {                                                                       \
      f32x4 s00 = (f32x4){0.f, 0.f, 0.f, 0.f};                                 \
      f32x4 s01 = s00, s10 = s00, s11 = s00;                                   \
      _Pragma("unroll")                                                        \
      for (int ks = 0; ks < 2; ++ks) {                                         \
        s00 = __builtin_amdgcn_mfma_f32_16x16x32_bf16(                         \
            KB[ks * 2 + 0], AQ[0][ks], s00, 0, 0, 0);                          \
        s01 = __builtin_amdgcn_mfma_f32_16x16x32_bf16(                         \
            KB[ks * 2 + 0], AQ[1][ks], s01, 0, 0, 0);                          \
        s10 = __builtin_amdgcn_mfma_f32_16x16x32_bf16(                         \
            KB[ks * 2 + 1], AQ[0][ks], s10, 0, 0, 0);                          \
        s11 = __builtin_amdgcn_mfma_f32_16x16x32_bf16(                         \
            KB[ks * 2 + 1], AQ[1][ks], s11, 0, 0, 0);                          \
      }                                                                        \
      _Pragma("unroll")                                                        \
      for (int h = 0; h < 2; ++h) {                                            \
        f32x4 sA = h ? s01 : s00; /* keys A*32+quad*8+r   */                   \
        f32x4 sB = h ? s11 : s10; /* keys A*32+quad*8+4+r */                   \
        float pv[8];                                                           \
        _Pragma("unroll")                                                      \
        for (int r = 0; r < 4; ++r) {                                          \
          float x0 = sA[r], x1 = sB[r];                                        \
          pv[r]     = __builtin_fmaf(0.5f * x0, x0, x0);                       \
          pv[4 + r] = __builtin_fmaf(0.5f * x1, x1, x1);                       \
        }                                                                      \
        if (diag) {                                                            \
          const int qrow = rh * 32 + h * 16 + low;                             \
          _Pragma("unroll")                                                    \
          for (int r = 0; r < 4; ++r) {                                        \
            if (((A) * 32 + quad * 8 + r) > qrow)     pv[r]     = 0.f;         \
            if (((A) * 32 + quad * 8 + 4 + r) > qrow) pv[4 + r] = 0.f;         \
          }                                                                    \
        }                                                                      \
        uint4 uu;                                                              \
        uu.x = cvtpk(pv[0], pv[1]); uu.y = cvtpk(pv[2], pv[3]);                \
        uu.z = cvtpk(pv[4], pv[5]); uu.w = cvtpk(pv[6], pv[7]);                \
        short8 pf = __builtin_bit_cast(short8, uu);                            \
        _Pragma("unroll")                                                      \
        for (int ft = 0; ft < 4; ++ft)                                         \
          OACC[h][ft] = __builtin_amdgcn_mfma_f32_16x16x32_bf16(               \
              VB[ft], pf, OACC[h][ft], 0, 0, 0);                               \
      }                                                                        \
    } while (0)

  // Barrier-free SW-pipelined loop, group-granularity double buffer.
  short8 k0f[4], v0f[4], k1f[4], v1f[4];
  {
    const int T0 = (p < nB) ? p : (p - nB);
    PRELOADG(T0, 0, k0f, v0f);
    PRELOADG(T0, 1, k1f, v1f);
  }
  for (int s = p; s <= 32; s += 2) {
    int sn = s + 2; if (sn > 32) sn = 32;          // clamp: tail loads harmless
    const int Tn = (sn < nB) ? sn : (sn - nB);
    const bool diag = (s == nB - 1) || (s == 32);
    if (s >= nB) COMPUTEG(k0f, v0f, 0, aqA, oaccA);
    else         COMPUTEG(k0f, v0f, 0, aqB, oaccB);
    PRELOADG(Tn, 0, k0f, v0f);                     // covered by group-1 compute
    if (s >= nB) COMPUTEG(k1f, v1f, 1, aqA, oaccA);
    else         COMPUTEG(k1f, v1f, 1, aqB, oaccB);
    PRELOADG(Tn, 1, k1f, v1f);                     // covered by next group-0
  }

  // ---- split-K merge via LDS (32KB) + epilogue ----
  __syncthreads();
  float* mw = mls + rh * 4096;
  if (p == 1) {
    #pragma unroll
    for (int h = 0; h < 2; ++h)
      #pragma unroll
      for (int ft = 0; ft < 4; ++ft) {
        *reinterpret_cast<f32x4*>(mw + ((0 * 8 + h * 4 + ft) * 256 + lane * 4)) =
            oaccA[h][ft];
        *reinterpret_cast<f32x4*>(mw + ((1 * 8 + h * 4 + ft) * 256 + lane * 4)) =
            oaccB[h][ft];
      }
  }
  __syncthreads();
  if (p == 0) {
    #pragma unroll
    for (int tsel = 0; tsel < 2; ++tsel) {
      const int qt = tsel ? (31 - qa) : qa;
      #pragma unroll
      for (int h = 0; h < 2; ++h)
        #pragma unroll
        for (int ft = 0; ft < 4; ++ft) {
          f32x4 o = tsel ? oaccB[h][ft] : oaccA[h][ft];
          f32x4 m = *reinterpret_cast<const f32x4*>(
              mw + ((tsel * 8 + h * 4 + ft) * 256 + lane * 4));
          o += m;
          *reinterpret_cast<f32x4*>(
              out + ((size_t)bh * SEQ + qt * 64 + rh * 32 + h * 16 + low) * DH +
              ft * 16 + quad * 4) = o;
        }
    }
  }
}

extern "C" void kernel_launch(void* const* d_in, const int* in_sizes, int n_in,
                              void* d_out, int out_size, void* d_ws, size_t ws_size,
                              hipStream_t stream)
{
  const float* q = (const float*)d_in[0];
  const float* k = (const float*)d_in[1];
  const float* v = (const float*)d_in[2];
  float* out = (float*)d_out;

  unsigned short* kb2 = (unsigned short*)d_ws;             // 8.4 MB bf16 packed
  unsigned short* vt2 = kb2 + (size_t)BH_N * SEQ * DH;     // 8.4 MB bf16 packed

  prep_kernel<<<dim3(32, BH_N), 256, 0, stream>>>(k, v, kb2, vt2);
  attn_kernel<<<dim3(16, BH_N), 256, 0, stream>>>(q, kb2, vt2, out);
}